// Round 1
// baseline (1294.086 us; speedup 1.0000x reference)
//
#include <hip/hip_runtime.h>
#include <hip/hip_bf16.h>

#define NNODES 100000
#define NEDGES 640000
#define DIM    128

// Pass 1: out[dst] += x[src] for every edge. 32 threads (half-wave) per edge,
// float4 per thread. Atomics are fire-and-forget (no return) -> L2-side f32 adds.
__global__ __launch_bounds__(256) void scatter_add_x(
    const float* __restrict__ x, const int* __restrict__ ei,
    float* __restrict__ out)
{
    int e = blockIdx.x * 8 + (threadIdx.x >> 5);
    if (e >= NEDGES) return;
    int lane = threadIdx.x & 31;
    int src = ei[e];           // edge_index[0][e]
    int dst = ei[NEDGES + e];  // edge_index[1][e]
    float4 v = reinterpret_cast<const float4*>(x + (size_t)src * DIM)[lane];
    float* o = out + (size_t)dst * DIM + (size_t)lane * 4;
    atomicAdd(o + 0, v.x);
    atomicAdd(o + 1, v.y);
    atomicAdd(o + 2, v.z);
    atomicAdd(o + 3, v.w);
}

// Pass 2: in-place out = out @ W^T. (torch Linear semantics: h[n,d] = sum_k agg[n,k]*W[d,k])
// W staged transposed in LDS with +1 pad (conflict-free), 16 rows per block staged
// in LDS before overwrite (in-place safe: all global reads precede the sync, all
// global writes follow it, blocks own disjoint rows).
__global__ __launch_bounds__(256) void gemm_inplace(
    float* __restrict__ out, const float* __restrict__ W)
{
    __shared__ float Wt[DIM][DIM + 1];   // Wt[k][d] = W[d][k], 66 KB
    __shared__ float rows[16][DIM + 1];  // 8.25 KB -> 74.3 KB total, 2 blocks/CU
    int tid = threadIdx.x;

    // Load W transposed. Read coalesced (consecutive k for fixed d);
    // write addr k*129+d -> bank (k+d)%32 walks banks: conflict-free.
    for (int i = tid; i < DIM * DIM; i += 256) {
        int d = i >> 7, k = i & 127;
        Wt[k][d] = W[i];
    }
    size_t base = (size_t)blockIdx.x * 16;
    float* g = out + base * DIM;
    for (int i = tid; i < 16 * DIM; i += 256) {
        rows[i >> 7][i & 127] = g[i];
    }
    __syncthreads();

    int rg = tid >> 4;   // row within block tile, 0..15
    int cg = tid & 15;   // column group, cols {cg, cg+16, ..., cg+112}
    float acc[8] = {};
    for (int k = 0; k < DIM; ++k) {
        float a = rows[rg][k];  // 4 distinct addrs/wave, distinct banks, 16-lane broadcast
#pragma unroll
        for (int j = 0; j < 8; ++j)
            acc[j] += a * Wt[k][cg + 16 * j];  // 16 consecutive banks, rg-broadcast
    }
    float* orow = out + (base + rg) * DIM;
#pragma unroll
    for (int j = 0; j < 8; ++j)
        orow[cg + 16 * j] = acc[j];
}

extern "C" void kernel_launch(void* const* d_in, const int* in_sizes, int n_in,
                              void* d_out, int out_size, void* d_ws, size_t ws_size,
                              hipStream_t stream) {
    const float* x  = (const float*)d_in[0];
    const float* W  = (const float*)d_in[1];
    const int*   ei = (const int*)d_in[2];
    float* out = (float*)d_out;

    hipMemsetAsync(out, 0, (size_t)NNODES * DIM * sizeof(float), stream);
    scatter_add_x<<<NEDGES / 8, 256, 0, stream>>>(x, ei, out);
    gemm_inplace<<<NNODES / 16, 256, 0, stream>>>(out, W);
}

// Round 2
// 585.689 us; speedup vs baseline: 2.2095x; 2.2095x over previous
//
#include <hip/hip_runtime.h>
#include <hip/hip_bf16.h>

#define NNODES 100000
#define NEDGES 640000
#define DIM    128
#define WSPAD  100352   // padded stride for 100001-entry arrays in ws

// ---- CSR build ------------------------------------------------------------

__global__ __launch_bounds__(256) void hist_kernel(const int* __restrict__ ei,
                                                   int* __restrict__ counts) {
    int e = blockIdx.x * 256 + threadIdx.x;
    if (e >= NEDGES) return;
    atomicAdd(&counts[ei[NEDGES + e]], 1);   // dst histogram (int atomics, cheap)
}

// Single-block exclusive scan of counts -> offsets (and cursor copy).
// Each of 1024 threads owns a 98-element segment; one 1024-wide LDS scan.
__global__ __launch_bounds__(1024) void scan_kernel(const int* __restrict__ counts,
                                                    int* __restrict__ offsets,
                                                    int* __restrict__ cursor) {
    __shared__ int sums[1024];
    int t = threadIdx.x;
    const int SEG = 98;                       // 1024*98 = 100352 >= 100001
    int base = t * SEG;
    int s = 0;
    for (int i = 0; i < SEG; ++i) {
        int idx = base + i;
        if (idx < NNODES) s += counts[idx];
    }
    sums[t] = s;
    __syncthreads();
    for (int off = 1; off < 1024; off <<= 1) {   // Hillis-Steele inclusive
        int v = (t >= off) ? sums[t - off] : 0;
        __syncthreads();
        sums[t] += v;
        __syncthreads();
    }
    int run = (t == 0) ? 0 : sums[t - 1];        // exclusive prefix of my segment
    for (int i = 0; i < SEG; ++i) {
        int idx = base + i;
        if (idx <= NNODES) {
            offsets[idx] = run;
            if (idx < NNODES) { cursor[idx] = run; run += counts[idx]; }
        }
    }
}

__global__ __launch_bounds__(256) void fill_kernel(const int* __restrict__ ei,
                                                   int* __restrict__ cursor,
                                                   int* __restrict__ csr_src) {
    int e = blockIdx.x * 256 + threadIdx.x;
    if (e >= NEDGES) return;
    int src = ei[e];
    int dst = ei[NEDGES + e];
    int pos = atomicAdd(&cursor[dst], 1);        // 640k return-atomics, low contention
    csr_src[pos] = src;
}

// ---- Atomic-free aggregation: out[i] = sum_{e: dst=i} x[src[e]] ----------
// One half-wave (32 lanes, float4 each) per node. Writes out exactly once.
__global__ __launch_bounds__(256) void gather_kernel(const float* __restrict__ x,
                                                     const int* __restrict__ offsets,
                                                     const int* __restrict__ csr_src,
                                                     float* __restrict__ out) {
    int node = blockIdx.x * 8 + (threadIdx.x >> 5);
    if (node >= NNODES) return;
    int lane = threadIdx.x & 31;
    int b = offsets[node], e = offsets[node + 1];
    float4 acc0 = {0.f, 0.f, 0.f, 0.f}, acc1 = {0.f, 0.f, 0.f, 0.f};
    int i = b;
    for (; i + 1 < e; i += 2) {                  // 2-deep for outstanding loads
        int s0 = csr_src[i], s1 = csr_src[i + 1];
        float4 v0 = reinterpret_cast<const float4*>(x + (size_t)s0 * DIM)[lane];
        float4 v1 = reinterpret_cast<const float4*>(x + (size_t)s1 * DIM)[lane];
        acc0.x += v0.x; acc0.y += v0.y; acc0.z += v0.z; acc0.w += v0.w;
        acc1.x += v1.x; acc1.y += v1.y; acc1.z += v1.z; acc1.w += v1.w;
    }
    if (i < e) {
        int s0 = csr_src[i];
        float4 v0 = reinterpret_cast<const float4*>(x + (size_t)s0 * DIM)[lane];
        acc0.x += v0.x; acc0.y += v0.y; acc0.z += v0.z; acc0.w += v0.w;
    }
    acc0.x += acc1.x; acc0.y += acc1.y; acc0.z += acc1.z; acc0.w += acc1.w;
    reinterpret_cast<float4*>(out + (size_t)node * DIM)[lane] = acc0;
}

// ---- In-place out = out @ W^T (torch Linear semantics) --------------------
// 64 rows/block, 4x8 register tile per thread -> VALU-bound, not LDS-bound.
__global__ __launch_bounds__(256) void gemm_kernel(float* __restrict__ out,
                                                   const float* __restrict__ W) {
    __shared__ float Wt[DIM][DIM + 4];   // Wt[k][d] = W[d][k]; stride 132 keeps
    __shared__ float rows[64][DIM + 4];  // float4 16B alignment + bank spread
    int tid = threadIdx.x;

    for (int i = tid; i < DIM * DIM; i += 256) {   // coalesced read, stride-132
        int d = i >> 7, k = i & 127;               // LDS write: bank walks by 1
        Wt[k][d] = W[i];
    }
    long base = (long)blockIdx.x * 64;
    const float* g = out + base * DIM;
    for (int i = tid; i < 64 * DIM; i += 256) {
        int r = i >> 7, k = i & 127;
        rows[r][k] = (base + r < NNODES) ? g[i] : 0.0f;  // stage before overwrite
    }
    __syncthreads();

    int tc = tid & 15;    // cols 8tc .. 8tc+7
    int tr = tid >> 4;    // rows 4tr .. 4tr+3
    float acc[4][8] = {};
    for (int k = 0; k < DIM; ++k) {
        float a0 = rows[4 * tr + 0][k];
        float a1 = rows[4 * tr + 1][k];
        float a2 = rows[4 * tr + 2][k];
        float a3 = rows[4 * tr + 3][k];
        float4 w0 = *reinterpret_cast<const float4*>(&Wt[k][8 * tc]);
        float4 w1 = *reinterpret_cast<const float4*>(&Wt[k][8 * tc + 4]);
        float w[8] = {w0.x, w0.y, w0.z, w0.w, w1.x, w1.y, w1.z, w1.w};
        float a[4] = {a0, a1, a2, a3};
#pragma unroll
        for (int ii = 0; ii < 4; ++ii)
#pragma unroll
            for (int jj = 0; jj < 8; ++jj)
                acc[ii][jj] += a[ii] * w[jj];
    }
#pragma unroll
    for (int ii = 0; ii < 4; ++ii) {
        long r = base + 4 * tr + ii;
        if (r < NNODES) {
            float4 o0 = {acc[ii][0], acc[ii][1], acc[ii][2], acc[ii][3]};
            float4 o1 = {acc[ii][4], acc[ii][5], acc[ii][6], acc[ii][7]};
            float4* p = reinterpret_cast<float4*>(out + r * DIM + 8 * tc);
            p[0] = o0;
            p[1] = o1;
        }
    }
}

extern "C" void kernel_launch(void* const* d_in, const int* in_sizes, int n_in,
                              void* d_out, int out_size, void* d_ws, size_t ws_size,
                              hipStream_t stream) {
    const float* x  = (const float*)d_in[0];
    const float* W  = (const float*)d_in[1];
    const int*   ei = (const int*)d_in[2];
    float* out = (float*)d_out;

    int* counts  = (int*)d_ws;            // [NNODES]
    int* offsets = counts + WSPAD;        // [NNODES+1]
    int* cursor  = offsets + WSPAD;       // [NNODES]
    int* csr_src = cursor + WSPAD;        // [NEDGES]   total ~3.8 MB of ws

    hipMemsetAsync(counts, 0, (size_t)NNODES * sizeof(int), stream);
    hist_kernel<<<(NEDGES + 255) / 256, 256, 0, stream>>>(ei, counts);
    scan_kernel<<<1, 1024, 0, stream>>>(counts, offsets, cursor);
    fill_kernel<<<(NEDGES + 255) / 256, 256, 0, stream>>>(ei, cursor, csr_src);
    gather_kernel<<<(NNODES + 7) / 8, 256, 0, stream>>>(x, offsets, csr_src, out);
    gemm_kernel<<<(NNODES + 63) / 64, 256, 0, stream>>>(out, W);
}

// Round 3
// 336.248 us; speedup vs baseline: 3.8486x; 1.7418x over previous
//
#include <hip/hip_runtime.h>
#include <hip/hip_bf16.h>

#define NNODES 100000
#define NEDGES 640000
#define DIM    128
#define WSPAD  100352            // padded stride for 100001-entry arrays in ws
#define NTILES ((NNODES + 255) / 256)   // 391

// ---- CSR build ------------------------------------------------------------

__global__ __launch_bounds__(256) void hist_kernel(const int* __restrict__ ei,
                                                   int* __restrict__ counts) {
    int e = blockIdx.x * 256 + threadIdx.x;
    if (e >= NEDGES) return;
    atomicAdd(&counts[ei[NEDGES + e]], 1);   // dst histogram (int atomics, L2-side)
}

// Phase 1: per-tile sums (coalesced, full grid).
__global__ __launch_bounds__(256) void tile_reduce(const int* __restrict__ counts,
                                                   int* __restrict__ tileSums) {
    __shared__ int s[256];
    int t = threadIdx.x;
    int i = blockIdx.x * 256 + t;
    s[t] = (i < NNODES) ? counts[i] : 0;
    __syncthreads();
    for (int off = 128; off > 0; off >>= 1) {
        if (t < off) s[t] += s[t + off];
        __syncthreads();
    }
    if (t == 0) tileSums[blockIdx.x] = s[0];
}

// Phase 2: exclusive scan of the 391 tile sums — one small block.
__global__ __launch_bounds__(512) void tile_scan(const int* __restrict__ tileSums,
                                                 int* __restrict__ tilePrefix) {
    __shared__ int s[512];
    int t = threadIdx.x;
    int v = (t < NTILES) ? tileSums[t] : 0;
    s[t] = v;
    __syncthreads();
    for (int off = 1; off < 512; off <<= 1) {
        int u = (t >= off) ? s[t - off] : 0;
        __syncthreads();
        s[t] += u;
        __syncthreads();
    }
    if (t < NTILES) tilePrefix[t] = s[t] - v;   // exclusive
}

// Phase 3: intra-tile exclusive scan + tile prefix -> offsets & cursor (coalesced).
__global__ __launch_bounds__(256) void tile_apply(const int* __restrict__ counts,
                                                  const int* __restrict__ tilePrefix,
                                                  int* __restrict__ offsets,
                                                  int* __restrict__ cursor) {
    __shared__ int s[256];
    int t = threadIdx.x;
    int i = blockIdx.x * 256 + t;
    int c = (i < NNODES) ? counts[i] : 0;
    s[t] = c;
    __syncthreads();
    for (int off = 1; off < 256; off <<= 1) {   // Hillis-Steele inclusive
        int u = (t >= off) ? s[t - off] : 0;
        __syncthreads();
        s[t] += u;
        __syncthreads();
    }
    if (i < NNODES) {
        int off = tilePrefix[blockIdx.x] + s[t] - c;  // exclusive prefix
        offsets[i] = off;
        cursor[i]  = off;
        if (i == NNODES - 1) offsets[NNODES] = off + c;  // total
    }
}

__global__ __launch_bounds__(256) void fill_kernel(const int* __restrict__ ei,
                                                   int* __restrict__ cursor,
                                                   int* __restrict__ csr_src) {
    int e = blockIdx.x * 256 + threadIdx.x;
    if (e >= NEDGES) return;
    int src = ei[e];
    int dst = ei[NEDGES + e];
    int pos = atomicAdd(&cursor[dst], 1);        // 640k return-atomics, low contention
    csr_src[pos] = src;
}

// ---- Atomic-free aggregation: out[i] = sum_{e: dst=i} x[src[e]] ----------
// One half-wave (32 lanes, float4 each) per node. Writes out exactly once.
__global__ __launch_bounds__(256) void gather_kernel(const float* __restrict__ x,
                                                     const int* __restrict__ offsets,
                                                     const int* __restrict__ csr_src,
                                                     float* __restrict__ out) {
    int node = blockIdx.x * 8 + (threadIdx.x >> 5);
    if (node >= NNODES) return;
    int lane = threadIdx.x & 31;
    int b = offsets[node], e = offsets[node + 1];
    float4 acc0 = {0.f, 0.f, 0.f, 0.f}, acc1 = {0.f, 0.f, 0.f, 0.f};
    int i = b;
    for (; i + 1 < e; i += 2) {                  // 2-deep for outstanding loads
        int s0 = csr_src[i], s1 = csr_src[i + 1];
        float4 v0 = reinterpret_cast<const float4*>(x + (size_t)s0 * DIM)[lane];
        float4 v1 = reinterpret_cast<const float4*>(x + (size_t)s1 * DIM)[lane];
        acc0.x += v0.x; acc0.y += v0.y; acc0.z += v0.z; acc0.w += v0.w;
        acc1.x += v1.x; acc1.y += v1.y; acc1.z += v1.z; acc1.w += v1.w;
    }
    if (i < e) {
        int s0 = csr_src[i];
        float4 v0 = reinterpret_cast<const float4*>(x + (size_t)s0 * DIM)[lane];
        acc0.x += v0.x; acc0.y += v0.y; acc0.z += v0.z; acc0.w += v0.w;
    }
    acc0.x += acc1.x; acc0.y += acc1.y; acc0.z += acc1.z; acc0.w += acc1.w;
    reinterpret_cast<float4*>(out + (size_t)node * DIM)[lane] = acc0;
}

// ---- In-place out = out @ W^T (torch Linear semantics) --------------------
// 64 rows/block, 4x8 register tile per thread -> VALU-bound, not LDS-bound.
__global__ __launch_bounds__(256) void gemm_kernel(float* __restrict__ out,
                                                   const float* __restrict__ W) {
    __shared__ float Wt[DIM][DIM + 4];   // Wt[k][d] = W[d][k]; stride 132 keeps
    __shared__ float rows[64][DIM + 4];  // float4 16B alignment + bank spread
    int tid = threadIdx.x;

    for (int i = tid; i < DIM * DIM; i += 256) {   // coalesced read
        int d = i >> 7, k = i & 127;
        Wt[k][d] = W[i];
    }
    long base = (long)blockIdx.x * 64;
    const float* g = out + base * DIM;
    for (int i = tid; i < 64 * DIM; i += 256) {
        int r = i >> 7, k = i & 127;
        rows[r][k] = (base + r < NNODES) ? g[i] : 0.0f;  // stage before overwrite
    }
    __syncthreads();

    int tc = tid & 15;    // cols 8tc .. 8tc+7
    int tr = tid >> 4;    // rows 4tr .. 4tr+3
    float acc[4][8] = {};
    for (int k = 0; k < DIM; ++k) {
        float a0 = rows[4 * tr + 0][k];
        float a1 = rows[4 * tr + 1][k];
        float a2 = rows[4 * tr + 2][k];
        float a3 = rows[4 * tr + 3][k];
        float4 w0 = *reinterpret_cast<const float4*>(&Wt[k][8 * tc]);
        float4 w1 = *reinterpret_cast<const float4*>(&Wt[k][8 * tc + 4]);
        float w[8] = {w0.x, w0.y, w0.z, w0.w, w1.x, w1.y, w1.z, w1.w};
        float a[4] = {a0, a1, a2, a3};
#pragma unroll
        for (int ii = 0; ii < 4; ++ii)
#pragma unroll
            for (int jj = 0; jj < 8; ++jj)
                acc[ii][jj] += a[ii] * w[jj];
    }
#pragma unroll
    for (int ii = 0; ii < 4; ++ii) {
        long r = base + 4 * tr + ii;
        if (r < NNODES) {
            float4 o0 = {acc[ii][0], acc[ii][1], acc[ii][2], acc[ii][3]};
            float4 o1 = {acc[ii][4], acc[ii][5], acc[ii][6], acc[ii][7]};
            float4* p = reinterpret_cast<float4*>(out + r * DIM + 8 * tc);
            p[0] = o0;
            p[1] = o1;
        }
    }
}

extern "C" void kernel_launch(void* const* d_in, const int* in_sizes, int n_in,
                              void* d_out, int out_size, void* d_ws, size_t ws_size,
                              hipStream_t stream) {
    const float* x  = (const float*)d_in[0];
    const float* W  = (const float*)d_in[1];
    const int*   ei = (const int*)d_in[2];
    float* out = (float*)d_out;

    int* counts     = (int*)d_ws;            // [NNODES]
    int* offsets    = counts + WSPAD;        // [NNODES+1]
    int* cursor     = offsets + WSPAD;       // [NNODES]
    int* csr_src    = cursor + WSPAD;        // [NEDGES]
    int* tileSums   = csr_src + NEDGES;      // [512]
    int* tilePrefix = tileSums + 512;        // [512]   total ~3.8 MB of ws

    hipMemsetAsync(counts, 0, (size_t)NNODES * sizeof(int), stream);
    hist_kernel<<<(NEDGES + 255) / 256, 256, 0, stream>>>(ei, counts);
    tile_reduce<<<NTILES, 256, 0, stream>>>(counts, tileSums);
    tile_scan<<<1, 512, 0, stream>>>(tileSums, tilePrefix);
    tile_apply<<<NTILES, 256, 0, stream>>>(counts, tilePrefix, offsets, cursor);
    fill_kernel<<<(NEDGES + 255) / 256, 256, 0, stream>>>(ei, cursor, csr_src);
    gather_kernel<<<(NNODES + 7) / 8, 256, 0, stream>>>(x, offsets, csr_src, out);
    gemm_kernel<<<(NNODES + 63) / 64, 256, 0, stream>>>(out, W);
}

// Round 4
// 233.241 us; speedup vs baseline: 5.5483x; 1.4416x over previous
//
#include <hip/hip_runtime.h>
#include <hip/hip_bf16.h>

#define NNODES 100000
#define NEDGES 640000
#define DIM    128
#define WSPAD  100352            // padded stride for 100001-entry arrays in ws
#define NTILES ((NNODES + 255) / 256)   // 391

typedef __attribute__((ext_vector_type(8))) __bf16 bf16x8;
typedef __attribute__((ext_vector_type(4))) float  f32x4;

// ---- CSR build ------------------------------------------------------------

__global__ __launch_bounds__(256) void hist_kernel(const int* __restrict__ ei,
                                                   int* __restrict__ counts) {
    int e = blockIdx.x * 256 + threadIdx.x;
    if (e >= NEDGES) return;
    atomicAdd(&counts[ei[NEDGES + e]], 1);   // dst histogram (int atomics, L2-side)
}

__global__ __launch_bounds__(256) void tile_reduce(const int* __restrict__ counts,
                                                   int* __restrict__ tileSums) {
    __shared__ int s[256];
    int t = threadIdx.x;
    int i = blockIdx.x * 256 + t;
    s[t] = (i < NNODES) ? counts[i] : 0;
    __syncthreads();
    for (int off = 128; off > 0; off >>= 1) {
        if (t < off) s[t] += s[t + off];
        __syncthreads();
    }
    if (t == 0) tileSums[blockIdx.x] = s[0];
}

__global__ __launch_bounds__(512) void tile_scan(const int* __restrict__ tileSums,
                                                 int* __restrict__ tilePrefix) {
    __shared__ int s[512];
    int t = threadIdx.x;
    int v = (t < NTILES) ? tileSums[t] : 0;
    s[t] = v;
    __syncthreads();
    for (int off = 1; off < 512; off <<= 1) {
        int u = (t >= off) ? s[t - off] : 0;
        __syncthreads();
        s[t] += u;
        __syncthreads();
    }
    if (t < NTILES) tilePrefix[t] = s[t] - v;   // exclusive
}

__global__ __launch_bounds__(256) void tile_apply(const int* __restrict__ counts,
                                                  const int* __restrict__ tilePrefix,
                                                  int* __restrict__ offsets,
                                                  int* __restrict__ cursor) {
    __shared__ int s[256];
    int t = threadIdx.x;
    int i = blockIdx.x * 256 + t;
    int c = (i < NNODES) ? counts[i] : 0;
    s[t] = c;
    __syncthreads();
    for (int off = 1; off < 256; off <<= 1) {
        int u = (t >= off) ? s[t - off] : 0;
        __syncthreads();
        s[t] += u;
        __syncthreads();
    }
    if (i < NNODES) {
        int off = tilePrefix[blockIdx.x] + s[t] - c;
        offsets[i] = off;
        cursor[i]  = off;
        if (i == NNODES - 1) offsets[NNODES] = off + c;
    }
}

__global__ __launch_bounds__(256) void fill_kernel(const int* __restrict__ ei,
                                                   int* __restrict__ cursor,
                                                   int* __restrict__ csr_src) {
    int e = blockIdx.x * 256 + threadIdx.x;
    if (e >= NEDGES) return;
    int src = ei[e];
    int dst = ei[NEDGES + e];
    int pos = atomicAdd(&cursor[dst], 1);
    csr_src[pos] = src;
}

// ---- Atomic-free aggregation: out[i] = sum_{e: dst=i} x[src[e]] ----------
__global__ __launch_bounds__(256) void gather_kernel(const float* __restrict__ x,
                                                     const int* __restrict__ offsets,
                                                     const int* __restrict__ csr_src,
                                                     float* __restrict__ out) {
    int node = blockIdx.x * 8 + (threadIdx.x >> 5);
    if (node >= NNODES) return;
    int lane = threadIdx.x & 31;
    int b = offsets[node], e = offsets[node + 1];
    float4 acc0 = {0.f, 0.f, 0.f, 0.f}, acc1 = {0.f, 0.f, 0.f, 0.f};
    int i = b;
    for (; i + 1 < e; i += 2) {
        int s0 = csr_src[i], s1 = csr_src[i + 1];
        float4 v0 = reinterpret_cast<const float4*>(x + (size_t)s0 * DIM)[lane];
        float4 v1 = reinterpret_cast<const float4*>(x + (size_t)s1 * DIM)[lane];
        acc0.x += v0.x; acc0.y += v0.y; acc0.z += v0.z; acc0.w += v0.w;
        acc1.x += v1.x; acc1.y += v1.y; acc1.z += v1.z; acc1.w += v1.w;
    }
    if (i < e) {
        int s0 = csr_src[i];
        float4 v0 = reinterpret_cast<const float4*>(x + (size_t)s0 * DIM)[lane];
        acc0.x += v0.x; acc0.y += v0.y; acc0.z += v0.z; acc0.w += v0.w;
    }
    acc0.x += acc1.x; acc0.y += acc1.y; acc0.z += acc1.z; acc0.w += acc1.w;
    reinterpret_cast<float4*>(out + (size_t)node * DIM)[lane] = acc0;
}

// ---- MFMA GEMM: in-place out = out @ W^T (bf16 inputs, fp32 accum) -------
// 64 rows/block, 4 waves; per wave 16 rows x 128 cols = 8 tiles of 16x16,
// K=128 in 4 chunks of 32. LDS: W bf16 [128][128] + agg bf16 [64][128],
// both XOR-swizzled at 16B granularity (chunk ^= row&7) -> conflict-free
// ds_read_b128 fragments. 48 KB LDS -> 3 blocks/CU.
__device__ __forceinline__ uint bf16pair(float a, float b) {
    uint ua = __float_as_uint(a), ub = __float_as_uint(b);
    ua = (ua + 0x7FFFu + ((ua >> 16) & 1u)) >> 16;   // RNE, inputs are finite
    ub = (ub + 0x7FFFu + ((ub >> 16) & 1u)) >> 16;
    return (ub << 16) | (ua & 0xFFFFu);
}

__global__ __launch_bounds__(256) void gemm_mfma(float* __restrict__ out,
                                                 const float* __restrict__ W) {
    __shared__ int4 w_lds[128 * 16];   // 32 KB: W[d][k] as bf16, swizzled
    __shared__ int4 a_lds[64 * 16];    // 16 KB: agg[r][k] as bf16, swizzled
    int tid = threadIdx.x;
    long base = (long)blockIdx.x * 64;

    // Stage W (16384 floats -> 2048 16B-chunks of 8 bf16)
    for (int i = 0; i < 8; ++i) {
        int c = i * 256 + tid;            // chunk id
        int d = c >> 4, k8 = c & 15;      // row d, 8-elem group k8
        const float4* p = reinterpret_cast<const float4*>(W + c * 8);
        float4 f0 = p[0], f1 = p[1];
        int4 v = {(int)bf16pair(f0.x, f0.y), (int)bf16pair(f0.z, f0.w),
                  (int)bf16pair(f1.x, f1.y), (int)bf16pair(f1.z, f1.w)};
        w_lds[(c & ~15) | (k8 ^ (d & 7))] = v;
    }
    // Stage agg tile (64 rows, read before overwrite; in-place safe)
    for (int i = 0; i < 4; ++i) {
        int c = i * 256 + tid;            // 0..1023
        int r = c >> 4, k8 = c & 15;
        float4 f0 = {0, 0, 0, 0}, f1 = {0, 0, 0, 0};
        if (base + r < NNODES) {
            const float4* p = reinterpret_cast<const float4*>(out + (base + r) * DIM + k8 * 8);
            f0 = p[0]; f1 = p[1];
        }
        int4 v = {(int)bf16pair(f0.x, f0.y), (int)bf16pair(f0.z, f0.w),
                  (int)bf16pair(f1.x, f1.y), (int)bf16pair(f1.z, f1.w)};
        a_lds[(c & ~15) | (k8 ^ (r & 7))] = v;
    }
    __syncthreads();

    int lane = tid & 63;
    int w    = tid >> 6;          // wave id: rows w*16 .. w*16+15 of the tile
    int rl   = lane & 15;         // A row / B col within 16
    int kg   = lane >> 4;         // k group: elements kg*8 .. kg*8+7 of the 32-chunk

    f32x4 acc[8] = {};
#pragma unroll
    for (int kc = 0; kc < 4; ++kc) {
        int arow = w * 16 + rl;
        int k8 = kc * 4 + kg;
        int4 araw = a_lds[arow * 16 + (k8 ^ (arow & 7))];
        bf16x8 af = *reinterpret_cast<bf16x8*>(&araw);
#pragma unroll
        for (int dt = 0; dt < 8; ++dt) {
            int d = dt * 16 + rl;
            int4 braw = w_lds[d * 16 + (k8 ^ (d & 7))];
            bf16x8 bf = *reinterpret_cast<bf16x8*>(&braw);
            acc[dt] = __builtin_amdgcn_mfma_f32_16x16x32_bf16(af, bf, acc[dt], 0, 0, 0);
        }
    }

    // C/D layout (m89-verified): col = lane&15, row = (lane>>4)*4 + reg
#pragma unroll
    for (int dt = 0; dt < 8; ++dt) {
#pragma unroll
        for (int j = 0; j < 4; ++j) {
            long r = base + w * 16 + kg * 4 + j;
            if (r < NNODES) out[r * DIM + dt * 16 + rl] = acc[dt][j];
        }
    }
}

extern "C" void kernel_launch(void* const* d_in, const int* in_sizes, int n_in,
                              void* d_out, int out_size, void* d_ws, size_t ws_size,
                              hipStream_t stream) {
    const float* x  = (const float*)d_in[0];
    const float* W  = (const float*)d_in[1];
    const int*   ei = (const int*)d_in[2];
    float* out = (float*)d_out;

    int* counts     = (int*)d_ws;            // [NNODES]
    int* offsets    = counts + WSPAD;        // [NNODES+1]
    int* cursor     = offsets + WSPAD;       // [NNODES]
    int* csr_src    = cursor + WSPAD;        // [NEDGES]
    int* tileSums   = csr_src + NEDGES;      // [512]
    int* tilePrefix = tileSums + 512;        // [512]

    hipMemsetAsync(counts, 0, (size_t)NNODES * sizeof(int), stream);
    hist_kernel<<<(NEDGES + 255) / 256, 256, 0, stream>>>(ei, counts);
    tile_reduce<<<NTILES, 256, 0, stream>>>(counts, tileSums);
    tile_scan<<<1, 512, 0, stream>>>(tileSums, tilePrefix);
    tile_apply<<<NTILES, 256, 0, stream>>>(counts, tilePrefix, offsets, cursor);
    fill_kernel<<<(NEDGES + 255) / 256, 256, 0, stream>>>(ei, cursor, csr_src);
    gather_kernel<<<(NNODES + 7) / 8, 256, 0, stream>>>(x, offsets, csr_src, out);
    gemm_mfma<<<(NNODES + 63) / 64, 256, 0, stream>>>(out, W);
}